// Round 1
// baseline (290.014 us; speedup 1.0000x reference)
//
#include <hip/hip_runtime.h>

typedef __bf16 bf16x8 __attribute__((ext_vector_type(8)));
typedef float f32x4 __attribute__((ext_vector_type(4)));

__device__ __forceinline__ unsigned short f2bf(float f) {
  unsigned int u = __float_as_uint(f);
  u += 0x7fffu + ((u >> 16) & 1u);
  return (unsigned short)(u >> 16);
}

__device__ __forceinline__ void load_lds16(const void* g, void* l) {
  __builtin_amdgcn_global_load_lds(
      (const __attribute__((address_space(1))) unsigned int*)g,
      (__attribute__((address_space(3))) unsigned int*)l, 16, 0, 0);
}

// ---------------- elementwise f32 -> bf16 ----------------
__global__ void cvt_x(const float* __restrict__ in, unsigned short* __restrict__ out) {
  size_t i = ((size_t)blockIdx.x * 256 + threadIdx.x) * 4;
  float4 v = *(const float4*)(in + i);
  ushort4 o;
  o.x = f2bf(v.x); o.y = f2bf(v.y); o.z = f2bf(v.z); o.w = f2bf(v.w);
  *(ushort4*)(out + i) = o;
}

// ---------------- transpose f32 [R][C] -> bf16 [C][R] ----------------
__global__ void tr_w(const float* __restrict__ in, unsigned short* __restrict__ out,
                     int ldin, int ldout) {
  __shared__ float tile[32][33];
  const int c0 = blockIdx.x * 32, r0 = blockIdx.y * 32;
  const int tx = threadIdx.x, ty = threadIdx.y;
#pragma unroll
  for (int j = 0; j < 4; ++j)
    tile[ty + j * 8][tx] = in[(size_t)(r0 + ty + j * 8) * ldin + c0 + tx];
  __syncthreads();
#pragma unroll
  for (int j = 0; j < 4; ++j)
    out[(size_t)(c0 + ty + j * 8) * ldout + r0 + tx] = f2bf(tile[tx][ty + j * 8]);
}

// ---------------- V slice of QKV -> VT [b*4+kv][128][2048] ----------------
__global__ void tr_v(const unsigned short* __restrict__ QKV, unsigned short* __restrict__ VT) {
  __shared__ unsigned short tile[32][33];
  const int z = blockIdx.z, b = z >> 2, kvh = z & 3;
  const unsigned short* in = QKV + (size_t)(b * 2048) * 3072 + 2560 + kvh * 128;
  unsigned short* out = VT + (size_t)z * 128 * 2048;
  const int c0 = blockIdx.x * 32, r0 = blockIdx.y * 32;
  const int tx = threadIdx.x, ty = threadIdx.y;
#pragma unroll
  for (int j = 0; j < 4; ++j)
    tile[ty + j * 8][tx] = in[(size_t)(r0 + ty + j * 8) * 3072 + c0 + tx];
  __syncthreads();
#pragma unroll
  for (int j = 0; j < 4; ++j)
    out[(size_t)(c0 + ty + j * 8) * 2048 + r0 + tx] = tile[tx][ty + j * 8];
}

// ---------------- bf16 GEMM: C[M][N] = A[M][K] * B^T[N][K] ----------------
// 128x128 tile, BK=64, 4 waves (2x2), 16x16x32 MFMA, XOR-swizzled LDS,
// staging via global_load_lds width-16 with pre-swizzled global source.
template <int OUTF32>
__global__ void gemm_bt(const unsigned short* __restrict__ A,
                        const unsigned short* __restrict__ B,
                        void* __restrict__ Cv, int M, int N, int K) {
  __shared__ __attribute__((aligned(16))) unsigned short As[128 * 64];
  __shared__ __attribute__((aligned(16))) unsigned short Bs[128 * 64];
  const int tid = threadIdx.x;
  const int lane = tid & 63;
  const int cl = lane & 15, rg = lane >> 4;
  const int wave = tid >> 6;
  const int bm = blockIdx.y, bn = blockIdx.x;
  const int wm = wave >> 1, wn = wave & 1;
  f32x4 acc[4][4] = {};
  const int nk = K >> 6;
  for (int kt = 0; kt < nk; ++kt) {
    const int k0 = kt << 6;
    __syncthreads();
#pragma unroll
    for (int i = 0; i < 8; ++i) {
      const int Ls = (i & 3) * 256 + tid;   // slot index within A or B region
      const int r = Ls >> 3, s = Ls & 7;
      const int c = s ^ (r & 7);            // logical chunk stored at physical s
      const unsigned short* src;
      unsigned short* dst;
      if (i < 4) {
        src = A + (size_t)(bm * 128 + r) * K + k0 + c * 8;
        dst = As + (((i & 3) * 256 + (tid & 0xC0)) << 3);
      } else {
        src = B + (size_t)(bn * 128 + r) * K + k0 + c * 8;
        dst = Bs + (((i & 3) * 256 + (tid & 0xC0)) << 3);
      }
      load_lds16(src, dst);
    }
    __syncthreads();
#pragma unroll
    for (int ks = 0; ks < 2; ++ks) {
      bf16x8 af[4], bfr[4];
#pragma unroll
      for (int m = 0; m < 4; ++m) {
        const int row = wm * 64 + m * 16 + cl;
        const int p = (ks * 4 + rg) ^ (row & 7);
        af[m] = *(const bf16x8*)(As + row * 64 + p * 8);
      }
#pragma unroll
      for (int n = 0; n < 4; ++n) {
        const int row = wn * 64 + n * 16 + cl;
        const int p = (ks * 4 + rg) ^ (row & 7);
        bfr[n] = *(const bf16x8*)(Bs + row * 64 + p * 8);
      }
#pragma unroll
      for (int m = 0; m < 4; ++m)
#pragma unroll
        for (int n = 0; n < 4; ++n)
          acc[m][n] = __builtin_amdgcn_mfma_f32_16x16x32_bf16(af[m], bfr[n], acc[m][n], 0, 0, 0);
    }
  }
#pragma unroll
  for (int m = 0; m < 4; ++m)
#pragma unroll
    for (int n = 0; n < 4; ++n)
#pragma unroll
      for (int i = 0; i < 4; ++i) {
        const int row = bm * 128 + wm * 64 + m * 16 + rg * 4 + i;
        const int col = bn * 128 + wn * 64 + n * 16 + cl;
        if (OUTF32)
          ((float*)Cv)[(size_t)row * N + col] = acc[m][n][i];
        else
          ((unsigned short*)Cv)[(size_t)row * N + col] = f2bf(acc[m][n][i]);
      }
}

// ---------------- causal GQA flash attention ----------------
// grid (qtile=32, head=16, batch=2), 256 threads = 4 waves, each wave 16 q-rows.
__global__ void attn(const unsigned short* __restrict__ QKV,
                     const unsigned short* __restrict__ VT,
                     unsigned short* __restrict__ O) {
  __shared__ __attribute__((aligned(16))) unsigned short Ks[64 * 128];
  __shared__ __attribute__((aligned(16))) unsigned short VTs[128 * 64];
  __shared__ __attribute__((aligned(16))) unsigned short Ps[4 * 16 * 64];
  const int T = 2048, LD = 3072, D = 2048;
  const int qt = blockIdx.x, h = blockIdx.y, b = blockIdx.z;
  const int kvh = h >> 2;
  const int tid = threadIdx.x, lane = tid & 63, wave = tid >> 6;
  const int cl = lane & 15, rg = lane >> 4;
  const int q0 = qt * 64;

  const unsigned short* Qp = QKV + (size_t)(b * T + q0 + wave * 16 + cl) * LD + h * 128;
  bf16x8 qf[4];
#pragma unroll
  for (int ks = 0; ks < 4; ++ks) qf[ks] = *(const bf16x8*)(Qp + ks * 32 + rg * 8);

  f32x4 o[8] = {};
  float mx[4] = {-1e30f, -1e30f, -1e30f, -1e30f};
  float lsum[4] = {0.f, 0.f, 0.f, 0.f};
  const unsigned short* Kbase = QKV + 2048 + kvh * 128;
  const unsigned short* Vbase = VT + (size_t)(b * 4 + kvh) * 128 * T;
  unsigned short* Pw = Ps + wave * (16 * 64);

  for (int kt = 0; kt <= qt; ++kt) {
    const int k0 = kt * 64;
    __syncthreads();
    // stage K tile [64][128] (16 chunks/row, swizzled)
#pragma unroll
    for (int i = 0; i < 4; ++i) {
      const int Ls = i * 256 + tid;
      const int r = Ls >> 4, s = Ls & 15;
      const int c = s ^ (r & 7);
      const unsigned short* src = Kbase + (size_t)(b * T + k0 + r) * LD + c * 8;
      load_lds16(src, Ks + ((i * 256 + (tid & 0xC0)) << 3));
    }
    // stage VT tile [128][64] (8 chunks/row, swizzled)
#pragma unroll
    for (int i = 0; i < 4; ++i) {
      const int Ls = i * 256 + tid;
      const int r = Ls >> 3, s = Ls & 7;
      const int c = s ^ (r & 7);
      const unsigned short* src = Vbase + (size_t)r * T + k0 + c * 8;
      load_lds16(src, VTs + ((i * 256 + (tid & 0xC0)) << 3));
    }
    __syncthreads();
    // S = Q K^T  (per wave: 16 q-rows x 64 kv)
    f32x4 sa[4] = {};
#pragma unroll
    for (int ks = 0; ks < 4; ++ks) {
#pragma unroll
      for (int n = 0; n < 4; ++n) {
        const int row = n * 16 + cl;
        const int p = (ks * 4 + rg) ^ (row & 7);
        const bf16x8 kf = *(const bf16x8*)(Ks + row * 128 + p * 8);
        sa[n] = __builtin_amdgcn_mfma_f32_16x16x32_bf16(qf[ks], kf, sa[n], 0, 0, 0);
      }
    }
    const float scale = 0.08838834764831845f;  // 1/sqrt(128)
    float pv[4][4];
    if (kt == qt) {
#pragma unroll
      for (int n = 0; n < 4; ++n) {
        const int colg = k0 + n * 16 + cl;
#pragma unroll
        for (int i = 0; i < 4; ++i) {
          const int rowg = q0 + wave * 16 + rg * 4 + i;
          pv[n][i] = (colg > rowg) ? -1e30f : sa[n][i] * scale;
        }
      }
    } else {
#pragma unroll
      for (int n = 0; n < 4; ++n)
#pragma unroll
        for (int i = 0; i < 4; ++i) pv[n][i] = sa[n][i] * scale;
    }
#pragma unroll
    for (int i = 0; i < 4; ++i) {
      float tm = fmaxf(fmaxf(pv[0][i], pv[1][i]), fmaxf(pv[2][i], pv[3][i]));
      tm = fmaxf(tm, __shfl_xor(tm, 1));
      tm = fmaxf(tm, __shfl_xor(tm, 2));
      tm = fmaxf(tm, __shfl_xor(tm, 4));
      tm = fmaxf(tm, __shfl_xor(tm, 8));
      const float mnew = fmaxf(mx[i], tm);
      const float alpha = __expf(mx[i] - mnew);
      mx[i] = mnew;
      float rs = 0.f;
#pragma unroll
      for (int n = 0; n < 4; ++n) {
        const float e = __expf(pv[n][i] - mnew);
        pv[n][i] = e;
        rs += e;
      }
      rs += __shfl_xor(rs, 1);
      rs += __shfl_xor(rs, 2);
      rs += __shfl_xor(rs, 4);
      rs += __shfl_xor(rs, 8);
      lsum[i] = lsum[i] * alpha + rs;
#pragma unroll
      for (int n = 0; n < 8; ++n) o[n][i] *= alpha;
    }
    // P -> bf16 -> per-wave LDS (swizzled rows of 64)
#pragma unroll
    for (int n = 0; n < 4; ++n)
#pragma unroll
      for (int i = 0; i < 4; ++i) {
        const int r = rg * 4 + i;
        const int ccol = n * 16 + cl;
        const int pch = (ccol >> 3) ^ (r & 7);
        Pw[r * 64 + pch * 8 + (ccol & 7)] = f2bf(pv[n][i]);
      }
    asm volatile("s_waitcnt lgkmcnt(0)" ::: "memory");
    __builtin_amdgcn_sched_barrier(0);
    // O += P * V
#pragma unroll
    for (int ks = 0; ks < 2; ++ks) {
      const int pp = (ks * 4 + rg) ^ (cl & 7);
      const bf16x8 pf = *(const bf16x8*)(Pw + cl * 64 + pp * 8);
#pragma unroll
      for (int n = 0; n < 8; ++n) {
        const int dr = n * 16 + cl;
        const int p2 = (ks * 4 + rg) ^ (dr & 7);
        const bf16x8 vf = *(const bf16x8*)(VTs + dr * 64 + p2 * 8);
        o[n] = __builtin_amdgcn_mfma_f32_16x16x32_bf16(pf, vf, o[n], 0, 0, 0);
      }
    }
  }
#pragma unroll
  for (int n = 0; n < 8; ++n)
#pragma unroll
    for (int i = 0; i < 4; ++i) {
      const int rowg = b * T + q0 + wave * 16 + rg * 4 + i;
      const int colg = h * 128 + n * 16 + cl;
      O[(size_t)rowg * D + colg] = f2bf(o[n][i] / lsum[i]);
    }
}

extern "C" void kernel_launch(void* const* d_in, const int* in_sizes, int n_in,
                              void* d_out, int out_size, void* d_ws, size_t ws_size,
                              hipStream_t stream) {
  const float* x = (const float*)d_in[0];
  const float* Wq = (const float*)d_in[1];
  const float* Wk = (const float*)d_in[2];
  const float* Wv = (const float*)d_in[3];
  const float* Wo = (const float*)d_in[4];
  float* out = (float*)d_out;

  char* ws = (char*)d_ws;
  unsigned short* xb    = (unsigned short*)(ws);                 // 16.78 MB (x bf16, later reused as attn O)
  unsigned short* WqkvT = (unsigned short*)(ws + 16777216);      // 12.58 MB  [3072][2048]
  unsigned short* WoT   = (unsigned short*)(ws + 29360128);      //  8.39 MB  [2048][2048]
  unsigned short* QKV   = (unsigned short*)(ws + 37748736);      // 25.17 MB  [4096][3072]
  unsigned short* VTb   = (unsigned short*)(ws + 62914560);      //  4.19 MB  [8][128][2048]

  cvt_x<<<dim3(8192), dim3(256), 0, stream>>>(x, xb);
  tr_w<<<dim3(64, 64), dim3(32, 8), 0, stream>>>(Wq, WqkvT, 2048, 2048);
  tr_w<<<dim3(16, 64), dim3(32, 8), 0, stream>>>(Wk, WqkvT + (size_t)2048 * 2048, 512, 2048);
  tr_w<<<dim3(16, 64), dim3(32, 8), 0, stream>>>(Wv, WqkvT + (size_t)2560 * 2048, 512, 2048);
  tr_w<<<dim3(64, 64), dim3(32, 8), 0, stream>>>(Wo, WoT, 2048, 2048);

  gemm_bt<0><<<dim3(24, 32), dim3(256), 0, stream>>>(xb, WqkvT, QKV, 4096, 3072, 2048);
  tr_v<<<dim3(4, 64, 8), dim3(32, 8), 0, stream>>>(QKV, VTb);
  attn<<<dim3(32, 16, 2), dim3(256), 0, stream>>>(QKV, VTb, xb);
  gemm_bt<1><<<dim3(16, 32), dim3(256), 0, stream>>>(xb, WoT, out, 4096, 2048, 2048);
}

// Round 2
// 201.084 us; speedup vs baseline: 1.4423x; 1.4423x over previous
//
#include <hip/hip_runtime.h>
#include <hip/hip_bf16.h>

typedef __bf16 bf16x8 __attribute__((ext_vector_type(8)));
typedef float f32x4 __attribute__((ext_vector_type(4)));

__device__ __forceinline__ unsigned short f2bf(float f) {
  unsigned int u = __float_as_uint(f);
  u += 0x7fffu + ((u >> 16) & 1u);
  return (unsigned short)(u >> 16);
}

__device__ __forceinline__ unsigned int pack2(float lo, float hi) {
  __hip_bfloat162 h = __float22bfloat162_rn(float2{lo, hi});
  return *(unsigned int*)&h;
}

__device__ __forceinline__ void load_lds16(const void* g, void* l) {
  __builtin_amdgcn_global_load_lds(
      (const __attribute__((address_space(1))) unsigned int*)g,
      (__attribute__((address_space(3))) unsigned int*)l, 16, 0, 0);
}

// ---------------- elementwise f32 -> bf16 ----------------
__global__ void cvt_x(const float* __restrict__ in, unsigned short* __restrict__ out) {
  size_t i = ((size_t)blockIdx.x * 256 + threadIdx.x) * 4;
  float4 v = *(const float4*)(in + i);
  ushort4 o;
  o.x = f2bf(v.x); o.y = f2bf(v.y); o.z = f2bf(v.z); o.w = f2bf(v.w);
  *(ushort4*)(out + i) = o;
}

// ---------------- transpose f32 [R][C] -> bf16 [C][R] ----------------
__global__ void tr_w(const float* __restrict__ in, unsigned short* __restrict__ out,
                     int ldin, int ldout) {
  __shared__ float tile[32][33];
  const int c0 = blockIdx.x * 32, r0 = blockIdx.y * 32;
  const int tx = threadIdx.x, ty = threadIdx.y;
#pragma unroll
  for (int j = 0; j < 4; ++j)
    tile[ty + j * 8][tx] = in[(size_t)(r0 + ty + j * 8) * ldin + c0 + tx];
  __syncthreads();
#pragma unroll
  for (int j = 0; j < 4; ++j)
    out[(size_t)(c0 + ty + j * 8) * ldout + r0 + tx] = f2bf(tile[tx][ty + j * 8]);
}

// ---------------- V slice of QKV -> VT [b*4+kv][128][2048] ----------------
__global__ void tr_v(const unsigned short* __restrict__ QKV, unsigned short* __restrict__ VT) {
  __shared__ unsigned short tile[32][33];
  const int z = blockIdx.z, b = z >> 2, kvh = z & 3;
  const unsigned short* in = QKV + (size_t)(b * 2048) * 3072 + 2560 + kvh * 128;
  unsigned short* out = VT + (size_t)z * 128 * 2048;
  const int c0 = blockIdx.x * 32, r0 = blockIdx.y * 32;
  const int tx = threadIdx.x, ty = threadIdx.y;
#pragma unroll
  for (int j = 0; j < 4; ++j)
    tile[ty + j * 8][tx] = in[(size_t)(r0 + ty + j * 8) * 3072 + c0 + tx];
  __syncthreads();
#pragma unroll
  for (int j = 0; j < 4; ++j)
    out[(size_t)(c0 + ty + j * 8) * 2048 + r0 + tx] = tile[tx][ty + j * 8];
}

// ---------------- bf16 GEMM: C[M][N] = A[M][K] * B^T[N][K] ----------------
template <int OUTF32>
__global__ void gemm_bt(const unsigned short* __restrict__ A,
                        const unsigned short* __restrict__ B,
                        void* __restrict__ Cv, int M, int N, int K) {
  __shared__ __attribute__((aligned(16))) unsigned short As[128 * 64];
  __shared__ __attribute__((aligned(16))) unsigned short Bs[128 * 64];
  const int tid = threadIdx.x;
  const int lane = tid & 63;
  const int cl = lane & 15, rg = lane >> 4;
  const int wave = tid >> 6;
  const int bm = blockIdx.y, bn = blockIdx.x;
  const int wm = wave >> 1, wn = wave & 1;
  f32x4 acc[4][4] = {};
  const int nk = K >> 6;
  for (int kt = 0; kt < nk; ++kt) {
    const int k0 = kt << 6;
    __syncthreads();
#pragma unroll
    for (int i = 0; i < 8; ++i) {
      const int Ls = (i & 3) * 256 + tid;
      const int r = Ls >> 3, s = Ls & 7;
      const int c = s ^ (r & 7);
      const unsigned short* src;
      unsigned short* dst;
      if (i < 4) {
        src = A + (size_t)(bm * 128 + r) * K + k0 + c * 8;
        dst = As + (((i & 3) * 256 + (tid & 0xC0)) << 3);
      } else {
        src = B + (size_t)(bn * 128 + r) * K + k0 + c * 8;
        dst = Bs + (((i & 3) * 256 + (tid & 0xC0)) << 3);
      }
      load_lds16(src, dst);
    }
    __syncthreads();
#pragma unroll
    for (int ks = 0; ks < 2; ++ks) {
      bf16x8 af[4], bfr[4];
#pragma unroll
      for (int m = 0; m < 4; ++m) {
        const int row = wm * 64 + m * 16 + cl;
        const int p = (ks * 4 + rg) ^ (row & 7);
        af[m] = *(const bf16x8*)(As + row * 64 + p * 8);
      }
#pragma unroll
      for (int n = 0; n < 4; ++n) {
        const int row = wn * 64 + n * 16 + cl;
        const int p = (ks * 4 + rg) ^ (row & 7);
        bfr[n] = *(const bf16x8*)(Bs + row * 64 + p * 8);
      }
#pragma unroll
      for (int m = 0; m < 4; ++m)
#pragma unroll
        for (int n = 0; n < 4; ++n)
          acc[m][n] = __builtin_amdgcn_mfma_f32_16x16x32_bf16(af[m], bfr[n], acc[m][n], 0, 0, 0);
    }
  }
#pragma unroll
  for (int m = 0; m < 4; ++m)
#pragma unroll
    for (int n = 0; n < 4; ++n)
#pragma unroll
      for (int i = 0; i < 4; ++i) {
        const int row = bm * 128 + wm * 64 + m * 16 + rg * 4 + i;
        const int col = bn * 128 + wn * 64 + n * 16 + cl;
        if (OUTF32)
          ((float*)Cv)[(size_t)row * N + col] = acc[m][n][i];
        else
          ((unsigned short*)Cv)[(size_t)row * N + col] = f2bf(acc[m][n][i]);
      }
}

// ---------------- causal GQA flash attention (swapped-operand, reg-P) ----------------
// Block: 4 waves x 16 q-rows = 64 q. Each block does q-tiles (j, 31-j): 33 k-iters, uniform.
// S^T = mfma(K, Q): col = q = lane&15 -> softmax lane-local + 2 shfl.
// P stays in registers: bf16-pair pack + 8-shuffle butterfly to PV B-fragment layout.
__global__ __launch_bounds__(256, 2) void attn(const unsigned short* __restrict__ QKV,
                                               const unsigned short* __restrict__ VT,
                                               unsigned short* __restrict__ O) {
  __shared__ __attribute__((aligned(16))) unsigned short Ks[2][64 * 128];
  __shared__ __attribute__((aligned(16))) unsigned short VTs[2][128 * 64];
  const int T = 2048, LD = 3072, D = 2048;
  const int jp = blockIdx.x, h = blockIdx.y, b = blockIdx.z;
  const int kvh = h >> 2;
  const int tid = threadIdx.x, lane = tid & 63, wave = tid >> 6;
  const int cl = lane & 15, rg = lane >> 4;
  const bool abit = (lane & 16) != 0, bbit = (lane & 32) != 0;
  const bool ab = abit != bbit;
  const unsigned short* Kbase = QKV + (size_t)b * T * LD + 2048 + kvh * 128;
  const unsigned short* Vbase = VT + (size_t)(b * 4 + kvh) * 128 * T;

  auto stage = [&](int sb, int k0) {
#pragma unroll
    for (int i = 0; i < 4; ++i) {
      const int Ls = i * 256 + tid;
      const int r = Ls >> 4, s = Ls & 15, c = s ^ (r & 7);
      load_lds16(Kbase + (size_t)(k0 + r) * LD + c * 8,
                 &Ks[sb][(i * 256 + (tid & 0xC0)) * 8]);
    }
#pragma unroll
    for (int i = 0; i < 4; ++i) {
      const int Ls = i * 256 + tid;
      const int r = Ls >> 3, s = Ls & 7, c = s ^ (r & 7);
      load_lds16(Vbase + (size_t)r * T + k0 + c * 8,
                 &VTs[sb][(i * 256 + (tid & 0xC0)) * 8]);
    }
  };

  const float scale = 0.08838834764831845f;  // 1/sqrt(128)

#pragma unroll 1
  for (int pass = 0; pass < 2; ++pass) {
    const int jt = pass ? (31 - jp) : jp;
    const int q0 = jt * 64;
    const int nkt = jt + 1;
    const int qrow = q0 + wave * 16 + cl;

    const unsigned short* Qp = QKV + (size_t)(b * T + qrow) * LD + h * 128;
    bf16x8 qf[4];
#pragma unroll
    for (int ks = 0; ks < 4; ++ks) qf[ks] = *(const bf16x8*)(Qp + ks * 32 + rg * 8);

    f32x4 o[8] = {};
    float m = -1e30f, l = 0.f;
    int buf = 0;

    stage(0, 0);
    __syncthreads();

#pragma unroll 1
    for (int kt = 0; kt < nkt; ++kt) {
      if (kt + 1 < nkt) stage(buf ^ 1, (kt + 1) * 64);

      // S^T = K * Q^T : sa[n] rows k = k0+n*16+rg*4+i, col q = cl
      f32x4 sa[4] = {};
      __builtin_amdgcn_s_setprio(1);
#pragma unroll
      for (int ks = 0; ks < 4; ++ks) {
#pragma unroll
        for (int n = 0; n < 4; ++n) {
          const int row = n * 16 + cl;
          const int p = (ks * 4 + rg) ^ (row & 7);
          const bf16x8 kf = *(const bf16x8*)(&Ks[buf][row * 128 + p * 8]);
          sa[n] = __builtin_amdgcn_mfma_f32_16x16x32_bf16(kf, qf[ks], sa[n], 0, 0, 0);
        }
      }
      __builtin_amdgcn_s_setprio(0);

      const int k0 = kt * 64;
      float p[4][4];
      float pmax = -1e30f;
      if (kt == jt) {
#pragma unroll
        for (int n = 0; n < 4; ++n)
#pragma unroll
          for (int i = 0; i < 4; ++i) {
            const int kg = k0 + n * 16 + rg * 4 + i;
            p[n][i] = (kg > qrow) ? -1e30f : sa[n][i] * scale;
            pmax = fmaxf(pmax, p[n][i]);
          }
      } else {
#pragma unroll
        for (int n = 0; n < 4; ++n)
#pragma unroll
          for (int i = 0; i < 4; ++i) {
            p[n][i] = sa[n][i] * scale;
            pmax = fmaxf(pmax, p[n][i]);
          }
      }
      pmax = fmaxf(pmax, __shfl_xor(pmax, 16));
      pmax = fmaxf(pmax, __shfl_xor(pmax, 32));

      if (!__all(pmax <= m + 8.f)) {  // T13 defer-max
        const float mnew = fmaxf(m, pmax);
        const float alpha = __expf(m - mnew);
        m = mnew;
        l *= alpha;
#pragma unroll
        for (int n2 = 0; n2 < 8; ++n2) o[n2] *= alpha;
      }

      float rs = 0.f;
#pragma unroll
      for (int n = 0; n < 4; ++n)
#pragma unroll
        for (int i = 0; i < 4; ++i) {
          p[n][i] = __expf(p[n][i] - m);
          rs += p[n][i];
        }
      rs += __shfl_xor(rs, 16);
      rs += __shfl_xor(rs, 32);
      l += rs;

      // pack P->bf16 pairs and butterfly into PV B-fragment layout
      unsigned int F[2][4];
#pragma unroll
      for (int ks2 = 0; ks2 < 2; ++ks2) {
        const unsigned int pk00 = pack2(p[2 * ks2][0], p[2 * ks2][1]);
        const unsigned int pk01 = pack2(p[2 * ks2][2], p[2 * ks2][3]);
        const unsigned int pk10 = pack2(p[2 * ks2 + 1][0], p[2 * ks2 + 1][1]);
        const unsigned int pk11 = pack2(p[2 * ks2 + 1][2], p[2 * ks2 + 1][3]);
        // stage 1: xor32 — send my n'=(b^1) values, keep n'=b
        const unsigned int s0 = bbit ? pk00 : pk10;
        const unsigned int s1 = bbit ? pk01 : pk11;
        const unsigned int r0 = (unsigned int)__shfl_xor((int)s0, 32);
        const unsigned int r1 = (unsigned int)__shfl_xor((int)s1, 32);
        const unsigned int gk0 = bbit ? pk10 : pk00;
        const unsigned int gk1 = bbit ? pk11 : pk01;
        // stage 2: xor16 — send (a!=b)?gk:gr, keep (a==b)?gk:gr
        const unsigned int t0 = ab ? gk0 : r0;
        const unsigned int t1 = ab ? gk1 : r1;
        const unsigned int u0 = (unsigned int)__shfl_xor((int)t0, 16);
        const unsigned int u1 = (unsigned int)__shfl_xor((int)t1, 16);
        const unsigned int k20 = ab ? r0 : gk0;
        const unsigned int k21 = ab ? r1 : gk1;
        F[ks2][0] = abit ? u0 : k20;
        F[ks2][1] = abit ? u1 : k21;
        F[ks2][2] = abit ? k20 : u0;
        F[ks2][3] = abit ? k21 : u1;
      }

      // O^T += V^T * P : o[n2] rows d = n2*16+rg*4+i, col q = cl
      __builtin_amdgcn_s_setprio(1);
#pragma unroll
      for (int ks2 = 0; ks2 < 2; ++ks2) {
        uint4 fu = make_uint4(F[ks2][0], F[ks2][1], F[ks2][2], F[ks2][3]);
        const bf16x8 pf = *(const bf16x8*)&fu;
#pragma unroll
        for (int n2 = 0; n2 < 8; ++n2) {
          const int dr = n2 * 16 + cl;
          const int p2 = (ks2 * 4 + rg) ^ (dr & 7);
          const bf16x8 vf = *(const bf16x8*)(&VTs[buf][dr * 64 + p2 * 8]);
          o[n2] = __builtin_amdgcn_mfma_f32_16x16x32_bf16(vf, pf, o[n2], 0, 0, 0);
        }
      }
      __builtin_amdgcn_s_setprio(0);

      __syncthreads();
      buf ^= 1;
    }

    const float rl = __builtin_amdgcn_rcpf(l);
#pragma unroll
    for (int n2 = 0; n2 < 8; ++n2) {
      ushort4 ov;
      ov.x = f2bf(o[n2][0] * rl);
      ov.y = f2bf(o[n2][1] * rl);
      ov.z = f2bf(o[n2][2] * rl);
      ov.w = f2bf(o[n2][3] * rl);
      *(ushort4*)(O + (size_t)(b * T + qrow) * D + h * 128 + n2 * 16 + rg * 4) = ov;
    }
  }
}

extern "C" void kernel_launch(void* const* d_in, const int* in_sizes, int n_in,
                              void* d_out, int out_size, void* d_ws, size_t ws_size,
                              hipStream_t stream) {
  const float* x = (const float*)d_in[0];
  const float* Wq = (const float*)d_in[1];
  const float* Wk = (const float*)d_in[2];
  const float* Wv = (const float*)d_in[3];
  const float* Wo = (const float*)d_in[4];
  float* out = (float*)d_out;

  char* ws = (char*)d_ws;
  unsigned short* xb    = (unsigned short*)(ws);                 // x bf16, later attn O
  unsigned short* WqkvT = (unsigned short*)(ws + 16777216);      // [3072][2048]
  unsigned short* WoT   = (unsigned short*)(ws + 29360128);      // [2048][2048]
  unsigned short* QKV   = (unsigned short*)(ws + 37748736);      // [4096][3072]
  unsigned short* VTb   = (unsigned short*)(ws + 62914560);      // [8][128][2048]

  cvt_x<<<dim3(8192), dim3(256), 0, stream>>>(x, xb);
  tr_w<<<dim3(64, 64), dim3(32, 8), 0, stream>>>(Wq, WqkvT, 2048, 2048);
  tr_w<<<dim3(16, 64), dim3(32, 8), 0, stream>>>(Wk, WqkvT + (size_t)2048 * 2048, 512, 2048);
  tr_w<<<dim3(16, 64), dim3(32, 8), 0, stream>>>(Wv, WqkvT + (size_t)2560 * 2048, 512, 2048);
  tr_w<<<dim3(64, 64), dim3(32, 8), 0, stream>>>(Wo, WoT, 2048, 2048);

  gemm_bt<0><<<dim3(24, 32), dim3(256), 0, stream>>>(xb, WqkvT, QKV, 4096, 3072, 2048);
  tr_v<<<dim3(4, 64, 8), dim3(32, 8), 0, stream>>>(QKV, VTb);
  attn<<<dim3(16, 16, 2), dim3(256), 0, stream>>>(QKV, VTb, xb);
  gemm_bt<1><<<dim3(16, 32), dim3(256), 0, stream>>>(xb, WoT, out, 4096, 2048, 2048);
}